// Round 8
// baseline (257.429 us; speedup 1.0000x reference)
//
#include <hip/hip_runtime.h>
#include <hip/hip_bf16.h>
#include <stdint.h>

typedef __bf16 bf16_t;
typedef bf16_t bf16x8 __attribute__((ext_vector_type(8)));
typedef bf16_t bf16x4 __attribute__((ext_vector_type(4)));
typedef float  f32x4  __attribute__((ext_vector_type(4)));

#define MFMA_BF16 __builtin_amdgcn_mfma_f32_16x16x32_bf16

constexpr int BB = 4, SS = 2048, HH = 8;
constexpr float QK_SCALE = 0.08838834764831845f;          // 1/sqrt(128)
constexpr float LOG2E    = 1.4426950408889634f;
constexpr float QSCL     = QK_SCALE * LOG2E;              // scores in log2 domain

__device__ __forceinline__ float exp2_fast(float x) {
#if __has_builtin(__builtin_amdgcn_exp2f)
    return __builtin_amdgcn_exp2f(x);
#else
    return __expf(x * 0.6931471805599453f);
#endif
}

// async global->LDS DMA, 16B per lane; lds ptr must be wave-uniform base
__device__ __forceinline__ void dma16(const bf16_t* g, bf16_t* l) {
    __builtin_amdgcn_global_load_lds(
        (const __attribute__((address_space(1))) void*)g,
        (__attribute__((address_space(3))) void*)l, 16, 0, 0);
}

// ---------------------------------------------------------------------------
// Prep: blocks 0..127 transpose weights (QSCL folded into WqT); blocks
// 128..895 convert q/k/v fp32 -> bf16 into Abf[3][8192][128].
// ---------------------------------------------------------------------------
__global__ void prep_kernel(const float* __restrict__ q, const float* __restrict__ k,
                            const float* __restrict__ v,
                            const float* __restrict__ Wq, const float* __restrict__ Wk,
                            const float* __restrict__ Wv, const float* __restrict__ Wo,
                            bf16_t* __restrict__ WqT, bf16_t* __restrict__ WkT,
                            bf16_t* __restrict__ WvT, bf16_t* __restrict__ WoT,
                            bf16_t* __restrict__ Abf)
{
    int bid = blockIdx.x, t = threadIdx.x;
    if (bid < 128) {
        __shared__ float tile[64][65];
        int m = bid >> 5, tl = bid & 31;
        const float* src; bf16_t* dst; int R, C, tr, tc; float scale = 1.0f;
        if (m < 3) {
            src = (m == 0) ? Wq : (m == 1) ? Wk : Wv;
            dst = (m == 0) ? WqT : (m == 1) ? WkT : WvT;
            R = 128; C = 1024; tr = tl >> 4; tc = tl & 15;
            if (m == 0) scale = QSCL;
        } else {
            src = Wo; dst = WoT; R = 1024; C = 128; tr = tl >> 1; tc = tl & 1;
        }
        int r0 = tr * 64, c0 = tc * 64;
        int rr = t >> 2, cc = (t & 3) * 16;
        const float4* s4 = (const float4*)(src + (size_t)(r0 + rr) * C + c0 + cc);
        #pragma unroll
        for (int i = 0; i < 4; ++i) {
            float4 f = s4[i];
            tile[rr][cc + 4 * i + 0] = f.x; tile[rr][cc + 4 * i + 1] = f.y;
            tile[rr][cc + 4 * i + 2] = f.z; tile[rr][cc + 4 * i + 3] = f.w;
        }
        __syncthreads();
        bf16x8 o0, o1;
        #pragma unroll
        for (int i = 0; i < 8; ++i) o0[i] = (bf16_t)(tile[cc + i][rr] * scale);
        #pragma unroll
        for (int i = 0; i < 8; ++i) o1[i] = (bf16_t)(tile[cc + 8 + i][rr] * scale);
        bf16_t* d = dst + (size_t)(c0 + rr) * R + r0 + cc;
        *(bf16x8*)d = o0;
        *(bf16x8*)(d + 8) = o1;
    } else {
        int bid2 = bid - 128;
        size_t base = (size_t)bid2 * 4096 + t * 16;
        int z = (int)(base >> 20);
        size_t off = base & 1048575;
        const float* s = (z == 0) ? q : (z == 1) ? k : v;
        const float4* s4 = (const float4*)(s + off);
        bf16_t* d = Abf + (size_t)z * 1048576 + off;
        float4 f0 = s4[0], f1 = s4[1], f2 = s4[2], f3 = s4[3];
        bf16x8 p0 = { (bf16_t)f0.x, (bf16_t)f0.y, (bf16_t)f0.z, (bf16_t)f0.w,
                      (bf16_t)f1.x, (bf16_t)f1.y, (bf16_t)f1.z, (bf16_t)f1.w };
        bf16x8 p1 = { (bf16_t)f2.x, (bf16_t)f2.y, (bf16_t)f2.z, (bf16_t)f2.w,
                      (bf16_t)f3.x, (bf16_t)f3.y, (bf16_t)f3.z, (bf16_t)f3.w };
        *(bf16x8*)d = p0;
        *(bf16x8*)(d + 8) = p1;
    }
}

// ---------------------------------------------------------------------------
// QKV projection (R4 structure): z=0 Q (scale folded), z=1 K, z=2 V^T.
// 128x128 tile; K=128 as 2x64 DMA double-buffered chunks (swizzled LDS).
// ---------------------------------------------------------------------------
__global__ __launch_bounds__(256, 2)
void proj_kernel(const bf16_t* __restrict__ Abf,
                 const bf16_t* __restrict__ WqT, const bf16_t* __restrict__ WkT,
                 const bf16_t* __restrict__ WvT,
                 const float* __restrict__ bq, const float* __restrict__ bk,
                 const float* __restrict__ bv,
                 bf16_t* __restrict__ Qh, bf16_t* __restrict__ Kh, bf16_t* __restrict__ VhT)
{
    __shared__ __align__(16) bf16_t a_s[2][128 * 64];
    __shared__ __align__(16) bf16_t b_s[2][128 * 64];
    const int z = blockIdx.z;
    const bf16_t* A    = Abf + (size_t)z * 1048576;
    const bf16_t* BT   = (z == 0) ? WqT : (z == 1) ? WkT : WvT;
    const float*  bias = (z == 0) ? bq  : (z == 1) ? bk  : bv;
    const float   bscale = (z == 0) ? QSCL : 1.0f;
    const int t = threadIdx.x, w = t >> 6, lane = t & 63, q = lane >> 4, ln = lane & 15;
    const int m0 = blockIdx.x * 128;
    const int n0 = blockIdx.y * 128;
    const int wm = (w & 1) * 64, wn = (w >> 1) * 64;

    auto stage = [&](int buf, int kb) {
        #pragma unroll
        for (int j = 0; j < 4; ++j) {
            int row = w * 32 + j * 8 + (lane >> 3);
            int u = (lane & 7) ^ (row & 7);
            dma16(A + (size_t)(m0 + row) * 128 + kb * 64 + u * 8,
                  &a_s[buf][(w * 32 + j * 8) * 64]);
            dma16(BT + (size_t)(n0 + row) * 128 + kb * 64 + u * 8,
                  &b_s[buf][(w * 32 + j * 8) * 64]);
        }
    };

    f32x4 acc[4][4] = {};
    stage(0, 0);
    __syncthreads();
    stage(1, 1);
    #pragma unroll
    for (int kb = 0; kb < 2; ++kb) {
        if (kb == 1) __syncthreads();
        const bf16_t* as = a_s[kb];
        const bf16_t* bs = b_s[kb];
        #pragma unroll
        for (int kc = 0; kc < 2; ++kc) {
            bf16x8 af[4], bfr[4];
            #pragma unroll
            for (int mi = 0; mi < 4; ++mi)
                af[mi] = *(const bf16x8*)&as[(wm + mi * 16 + ln) * 64 + (((kc * 4 + q) ^ (ln & 7)) * 8)];
            #pragma unroll
            for (int ni = 0; ni < 4; ++ni)
                bfr[ni] = *(const bf16x8*)&bs[(wn + ni * 16 + ln) * 64 + (((kc * 4 + q) ^ (ln & 7)) * 8)];
            if (z != 2) {
                #pragma unroll
                for (int mi = 0; mi < 4; ++mi)
                    #pragma unroll
                    for (int ni = 0; ni < 4; ++ni)
                        acc[mi][ni] = MFMA_BF16(af[mi], bfr[ni], acc[mi][ni], 0, 0, 0);
            } else {
                #pragma unroll
                for (int mi = 0; mi < 4; ++mi)
                    #pragma unroll
                    for (int ni = 0; ni < 4; ++ni)
                        acc[mi][ni] = MFMA_BF16(bfr[ni], af[mi], acc[mi][ni], 0, 0, 0);
            }
        }
    }
    bf16_t* out = (z == 0) ? Qh : (z == 1) ? Kh : VhT;
    if (z != 2) {
        #pragma unroll
        for (int ni = 0; ni < 4; ++ni) {
            int col = n0 + wn + ni * 16 + ln;
            int h = col >> 7, d = col & 127;
            float bvv = bias[col] * bscale;
            #pragma unroll
            for (int mi = 0; mi < 4; ++mi) {
                int mbase = m0 + wm + mi * 16 + q * 4;
                int b = mbase >> 11, s = mbase & 2047;
                #pragma unroll
                for (int r = 0; r < 4; ++r)
                    out[((size_t)(b * HH + h) * SS + (s + r)) * 128 + d] =
                        (bf16_t)(acc[mi][ni][r] + bvv);
            }
        }
    } else {
        #pragma unroll
        for (int ni = 0; ni < 4; ++ni) {
            #pragma unroll
            for (int r = 0; r < 4; ++r) {
                int col = n0 + wn + ni * 16 + q * 4 + r;   // dout index
                int h = col >> 7, d = col & 127;
                float bvv = bias[col];
                #pragma unroll
                for (int mi = 0; mi < 4; ++mi) {
                    int mg = m0 + wm + mi * 16 + ln;        // s index
                    int b = mg >> 11, s = mg & 2047;
                    out[((size_t)(b * HH + h) * 128 + d) * SS + s] =
                        (bf16_t)(acc[mi][ni][r] + bvv);
                }
            }
        }
    }
}

// ---------------------------------------------------------------------------
// Attention (R4 + padded P strip): block = (bh, 128 q-rows), 4 waves x 32
// rows, KV tiles of 64. DMA double-buffered swizzled K/V, 1 barrier/iter.
// P strip row stride 72 elems (144 B) -> per-row 4-bank shift kills the
// 8-way pf-read / 4-way P-write conflicts of the 128 B-row layout.
// LDS 51.2 KB -> 2 blocks/CU.
// ---------------------------------------------------------------------------
__global__ __launch_bounds__(256, 2)
void attn_kernel(const bf16_t* __restrict__ Qh, const bf16_t* __restrict__ Kh,
                 const bf16_t* __restrict__ VhT, bf16_t* __restrict__ Aout)
{
    __shared__ __align__(16) bf16_t k_s[2][64 * 128];
    __shared__ __align__(16) bf16_t v_s[2][128 * 64];
    __shared__ __align__(16) bf16_t p_s[4 * 32 * 72];   // 72-elem row stride
    const int t = threadIdx.x;
    const int w = t >> 6, lane = t & 63, q = lane >> 4, ln = lane & 15;
    const int bh = blockIdx.y;
    const int q0 = blockIdx.x * 128;
    const size_t hb = (size_t)bh * SS * 128;

    bf16x8 qf[2][4];
    #pragma unroll
    for (int rg = 0; rg < 2; ++rg) {
        const bf16_t* qrow = Qh + hb + (size_t)(q0 + w * 32 + rg * 16 + ln) * 128;
        #pragma unroll
        for (int kc = 0; kc < 4; ++kc)
            qf[rg][kc] = *(const bf16x8*)(qrow + kc * 32 + q * 8);
    }
    const bf16_t one = (bf16_t)1.0f;
    bf16x8 ones = { one, one, one, one, one, one, one, one };
    f32x4 o[2][8] = {};
    f32x4 ol[2] = {};
    bf16_t* pw = &p_s[w * 32 * 72];

    auto stage = [&](int buf, int kv0) {
        #pragma unroll
        for (int j = 0; j < 4; ++j) {           // K: 4 rows per inst
            int row = w * 16 + j * 4 + (lane >> 4);
            int blk = (lane & 15) ^ (row & 7);
            dma16(Kh + hb + (size_t)(kv0 + row) * 128 + blk * 8,
                  &k_s[buf][(w * 16 + j * 4) * 128]);
        }
        #pragma unroll
        for (int j = 0; j < 4; ++j) {           // V^T: 8 rows per inst
            int row = w * 32 + j * 8 + (lane >> 3);
            int blk = (lane & 7) ^ (row & 7);
            dma16(VhT + hb + (size_t)row * SS + kv0 + blk * 8,
                  &v_s[buf][(w * 32 + j * 8) * 64]);
        }
    };

    stage(0, 0);
    for (int it = 0; it < SS / 64; ++it) {
        int cur = it & 1;
        __syncthreads();                        // publish tile `it` (drains DMA)
        if (it + 1 < SS / 64) stage(cur ^ 1, (it + 1) * 64);
        const bf16_t* ks = &k_s[cur][0];
        const bf16_t* vs = &v_s[cur][0];
        // S^T = K * Q^T : C[key][qrow]  (log2-domain scores)
        f32x4 sc[2][4] = {};
        #pragma unroll
        for (int kc = 0; kc < 4; ++kc) {
            #pragma unroll
            for (int nt = 0; nt < 4; ++nt) {
                int row = nt * 16 + ln;
                bf16x8 kf = *(const bf16x8*)&ks[row * 128 + (((kc * 4 + q) ^ (ln & 7)) * 8)];
                sc[0][nt] = MFMA_BF16(kf, qf[0][kc], sc[0][nt], 0, 0, 0);
                sc[1][nt] = MFMA_BF16(kf, qf[1][kc], sc[1][nt], 0, 0, 0);
            }
        }
        // exp2 + swizzled P write (b64), padded rows
        #pragma unroll
        for (int rg = 0; rg < 2; ++rg) {
            #pragma unroll
            for (int nt = 0; nt < 4; ++nt) {
                bf16x4 pk;
                #pragma unroll
                for (int r = 0; r < 4; ++r)
                    pk[r] = (bf16_t)exp2_fast(sc[rg][nt][r]);
                int row = rg * 16 + ln;
                int blk = (2 * nt + (q >> 1)) ^ (row & 7);
                *(bf16x4*)&pw[row * 72 + blk * 8 + (q & 1) * 4] = pk;
            }
        }
        // PV + rowsum(l) via ones-MFMA; p wave-private: no barrier
        #pragma unroll
        for (int c2 = 0; c2 < 2; ++c2) {
            int pblk = (c2 * 4 + q) ^ (ln & 7);
            bf16x8 pf0 = *(const bf16x8*)&pw[ln * 72 + pblk * 8];
            bf16x8 pf1 = *(const bf16x8*)&pw[(16 + ln) * 72 + pblk * 8];
            ol[0] = MFMA_BF16(pf0, ones, ol[0], 0, 0, 0);
            ol[1] = MFMA_BF16(pf1, ones, ol[1], 0, 0, 0);
            #pragma unroll
            for (int dt = 0; dt < 8; ++dt) {
                int vrow = dt * 16 + ln;
                bf16x8 vf = *(const bf16x8*)&vs[vrow * 64 + (((c2 * 4 + q) ^ (vrow & 7)) * 8)];
                o[0][dt] = MFMA_BF16(pf0, vf, o[0][dt], 0, 0, 0);
                o[1][dt] = MFMA_BF16(pf1, vf, o[1][dt], 0, 0, 0);
            }
        }
    }
    const int b = bh >> 3, h = bh & 7;
    #pragma unroll
    for (int rg = 0; rg < 2; ++rg) {
        #pragma unroll
        for (int r = 0; r < 4; ++r) {
            float inv = 1.0f / ol[rg][r];
            int s = q0 + w * 32 + rg * 16 + q * 4 + r;
            bf16_t* dst = Aout + ((size_t)(b * SS + s)) * 1024 + h * 128;
            #pragma unroll
            for (int dt = 0; dt < 8; ++dt)
                dst[dt * 16 + ln] = (bf16_t)(o[rg][dt][r] * inv);
        }
    }
}

// ---------------------------------------------------------------------------
// Output projection: [8192][1024] @ WoT^T + bo -> fp32 d_out. Full K=1024,
// 16 DMA double-buffered steps. Tile 16m x 128n, 512 blocks, 4 blk/CU.
// ---------------------------------------------------------------------------
__global__ __launch_bounds__(256, 4)
void out_gemm(const bf16_t* __restrict__ A, const bf16_t* __restrict__ BT,
              const float* __restrict__ bias, float* __restrict__ out)
{
    __shared__ __align__(16) bf16_t a_s[2][16 * 64];
    __shared__ __align__(16) bf16_t b_s[2][128 * 64];
    const int t = threadIdx.x, w = t >> 6, lane = t & 63, q = lane >> 4, ln = lane & 15;
    const int m0 = blockIdx.x * 16;
    const int nh = w * 32;
    f32x4 acc[2] = {};

    auto stage = [&](int buf, int kk) {
        if (w == 0) {
            #pragma unroll
            for (int j = 0; j < 2; ++j) {
                int row = j * 8 + (lane >> 3);
                int u = (lane & 7) ^ (row & 7);
                dma16(A + (size_t)(m0 + row) * 1024 + kk + u * 8, &a_s[buf][(j * 8) * 64]);
            }
        }
        #pragma unroll
        for (int j = 0; j < 4; ++j) {
            int row = w * 32 + j * 8 + (lane >> 3);
            int u = (lane & 7) ^ (row & 7);
            dma16(BT + (size_t)row * 1024 + kk + u * 8, &b_s[buf][(w * 32 + j * 8) * 64]);
        }
    };

    stage(0, 0);
    for (int kb = 0; kb < 16; ++kb) {
        __syncthreads();
        if (kb < 15) stage((kb + 1) & 1, (kb + 1) * 64);
        const bf16_t* as = a_s[kb & 1];
        const bf16_t* bs = b_s[kb & 1];
        #pragma unroll
        for (int kc = 0; kc < 2; ++kc) {
            bf16x8 af = *(const bf16x8*)&as[ln * 64 + (((kc * 4 + q) ^ (ln & 7)) * 8)];
            #pragma unroll
            for (int ni = 0; ni < 2; ++ni) {
                int brow = nh + ni * 16 + ln;
                bf16x8 bfr = *(const bf16x8*)&bs[brow * 64 + (((kc * 4 + q) ^ (ln & 7)) * 8)];
                acc[ni] = MFMA_BF16(af, bfr, acc[ni], 0, 0, 0);
            }
        }
    }
    #pragma unroll
    for (int ni = 0; ni < 2; ++ni) {
        int col = nh + ni * 16 + ln;
        float bv = bias[col];
        #pragma unroll
        for (int r = 0; r < 4; ++r)
            out[(size_t)(m0 + q * 4 + r) * 128 + col] = acc[ni][r] + bv;
    }
}

// ---------------------------------------------------------------------------
extern "C" void kernel_launch(void* const* d_in, const int* in_sizes, int n_in,
                              void* d_out, int out_size, void* d_ws, size_t ws_size,
                              hipStream_t stream)
{
    const float* q  = (const float*)d_in[0];
    const float* k  = (const float*)d_in[1];
    const float* v  = (const float*)d_in[2];
    const float* Wq = (const float*)d_in[3];
    const float* bq = (const float*)d_in[4];
    const float* Wk = (const float*)d_in[5];
    const float* bk = (const float*)d_in[6];
    const float* Wv = (const float*)d_in[7];
    const float* bv = (const float*)d_in[8];
    const float* Wo = (const float*)d_in[9];
    const float* bo = (const float*)d_in[10];
    float* out = (float*)d_out;

    char* ws = (char*)d_ws;
    bf16_t* WqT  = (bf16_t*)(ws + 0 * (1 << 18));
    bf16_t* WkT  = (bf16_t*)(ws + 1 * (1 << 18));
    bf16_t* WvT  = (bf16_t*)(ws + 2 * (1 << 18));
    bf16_t* WoT  = (bf16_t*)(ws + 3 * (1 << 18));
    bf16_t* Abf  = (bf16_t*)(ws + (1 << 20));                   // [3][8192][128]
    bf16_t* Qh   = (bf16_t*)(ws + (1 << 23));                   // [B][H][S][128]
    bf16_t* Kh   = (bf16_t*)(ws + (1 << 23) + 1 * (1 << 24));   // [B][H][S][128]
    bf16_t* VhT  = (bf16_t*)(ws + (1 << 23) + 2 * (1 << 24));   // [B][H][128][S]
    bf16_t* Aout = (bf16_t*)(ws + (1 << 23) + 3 * (1 << 24));   // [B*S][1024]

    prep_kernel<<<896, 256, 0, stream>>>(q, k, v, Wq, Wk, Wv, Wo,
                                         WqT, WkT, WvT, WoT, Abf);
    proj_kernel<<<dim3(64, 8, 3), 256, 0, stream>>>(Abf, WqT, WkT, WvT,
                                                    bq, bk, bv, Qh, Kh, VhT);
    attn_kernel<<<dim3(SS / 128, BB * HH), 256, 0, stream>>>(Qh, Kh, VhT, Aout);
    out_gemm<<<512, 256, 0, stream>>>(Aout, WoT, bo, out);
}

// Round 9
// 184.533 us; speedup vs baseline: 1.3950x; 1.3950x over previous
//
#include <hip/hip_runtime.h>
#include <hip/hip_bf16.h>
#include <stdint.h>

typedef __bf16 bf16_t;
typedef bf16_t bf16x8 __attribute__((ext_vector_type(8)));
typedef bf16_t bf16x4 __attribute__((ext_vector_type(4)));
typedef float  f32x4  __attribute__((ext_vector_type(4)));

#define MFMA_BF16 __builtin_amdgcn_mfma_f32_16x16x32_bf16

constexpr int BB = 4, SS = 2048, HH = 8;
constexpr float QK_SCALE = 0.08838834764831845f;          // 1/sqrt(128)
constexpr float LOG2E    = 1.4426950408889634f;
constexpr float QSCL     = QK_SCALE * LOG2E;              // scores in log2 domain

__device__ __forceinline__ float exp2_fast(float x) {
#if __has_builtin(__builtin_amdgcn_exp2f)
    return __builtin_amdgcn_exp2f(x);
#else
    return __expf(x * 0.6931471805599453f);
#endif
}

// async global->LDS DMA, 16B per lane; lds ptr must be wave-uniform base
__device__ __forceinline__ void dma16(const bf16_t* g, bf16_t* l) {
    __builtin_amdgcn_global_load_lds(
        (const __attribute__((address_space(1))) void*)g,
        (__attribute__((address_space(3))) void*)l, 16, 0, 0);
}

// ---------------------------------------------------------------------------
// Prep: blocks 0..127 transpose weights (QSCL folded into WqT); blocks
// 128..895 convert q/k/v fp32 -> bf16 into Abf[3][8192][128].
// ---------------------------------------------------------------------------
__global__ void prep_kernel(const float* __restrict__ q, const float* __restrict__ k,
                            const float* __restrict__ v,
                            const float* __restrict__ Wq, const float* __restrict__ Wk,
                            const float* __restrict__ Wv, const float* __restrict__ Wo,
                            bf16_t* __restrict__ WqT, bf16_t* __restrict__ WkT,
                            bf16_t* __restrict__ WvT, bf16_t* __restrict__ WoT,
                            bf16_t* __restrict__ Abf)
{
    int bid = blockIdx.x, t = threadIdx.x;
    if (bid < 128) {
        __shared__ float tile[64][65];
        int m = bid >> 5, tl = bid & 31;
        const float* src; bf16_t* dst; int R, C, tr, tc; float scale = 1.0f;
        if (m < 3) {
            src = (m == 0) ? Wq : (m == 1) ? Wk : Wv;
            dst = (m == 0) ? WqT : (m == 1) ? WkT : WvT;
            R = 128; C = 1024; tr = tl >> 4; tc = tl & 15;
            if (m == 0) scale = QSCL;
        } else {
            src = Wo; dst = WoT; R = 1024; C = 128; tr = tl >> 1; tc = tl & 1;
        }
        int r0 = tr * 64, c0 = tc * 64;
        int rr = t >> 2, cc = (t & 3) * 16;
        const float4* s4 = (const float4*)(src + (size_t)(r0 + rr) * C + c0 + cc);
        #pragma unroll
        for (int i = 0; i < 4; ++i) {
            float4 f = s4[i];
            tile[rr][cc + 4 * i + 0] = f.x; tile[rr][cc + 4 * i + 1] = f.y;
            tile[rr][cc + 4 * i + 2] = f.z; tile[rr][cc + 4 * i + 3] = f.w;
        }
        __syncthreads();
        bf16x8 o0, o1;
        #pragma unroll
        for (int i = 0; i < 8; ++i) o0[i] = (bf16_t)(tile[cc + i][rr] * scale);
        #pragma unroll
        for (int i = 0; i < 8; ++i) o1[i] = (bf16_t)(tile[cc + 8 + i][rr] * scale);
        bf16_t* d = dst + (size_t)(c0 + rr) * R + r0 + cc;
        *(bf16x8*)d = o0;
        *(bf16x8*)(d + 8) = o1;
    } else {
        int bid2 = bid - 128;
        size_t base = (size_t)bid2 * 4096 + t * 16;
        int z = (int)(base >> 20);
        size_t off = base & 1048575;
        const float* s = (z == 0) ? q : (z == 1) ? k : v;
        const float4* s4 = (const float4*)(s + off);
        bf16_t* d = Abf + (size_t)z * 1048576 + off;
        float4 f0 = s4[0], f1 = s4[1], f2 = s4[2], f3 = s4[3];
        bf16x8 p0 = { (bf16_t)f0.x, (bf16_t)f0.y, (bf16_t)f0.z, (bf16_t)f0.w,
                      (bf16_t)f1.x, (bf16_t)f1.y, (bf16_t)f1.z, (bf16_t)f1.w };
        bf16x8 p1 = { (bf16_t)f2.x, (bf16_t)f2.y, (bf16_t)f2.z, (bf16_t)f2.w,
                      (bf16_t)f3.x, (bf16_t)f3.y, (bf16_t)f3.z, (bf16_t)f3.w };
        *(bf16x8*)d = p0;
        *(bf16x8*)(d + 8) = p1;
    }
}

// ---------------------------------------------------------------------------
// QKV projection: z=0 Q (scale folded), z=1 K, z=2 V^T. 128x128 tile;
// K=128 as 2x64 DMA double-buffered chunks (swizzled LDS). All z use
// swapped MFMA(bfr, af) -> C rows = n(d), cols = m(s); z!=2 epilogue packs
// 4 consecutive d per lane into b64 stores (16 stores vs 64 scalar).
// ---------------------------------------------------------------------------
__global__ __launch_bounds__(256, 2)
void proj_kernel(const bf16_t* __restrict__ Abf,
                 const bf16_t* __restrict__ WqT, const bf16_t* __restrict__ WkT,
                 const bf16_t* __restrict__ WvT,
                 const float* __restrict__ bq, const float* __restrict__ bk,
                 const float* __restrict__ bv,
                 bf16_t* __restrict__ Qh, bf16_t* __restrict__ Kh, bf16_t* __restrict__ VhT)
{
    __shared__ __align__(16) bf16_t a_s[2][128 * 64];
    __shared__ __align__(16) bf16_t b_s[2][128 * 64];
    const int z = blockIdx.z;
    const bf16_t* A    = Abf + (size_t)z * 1048576;
    const bf16_t* BT   = (z == 0) ? WqT : (z == 1) ? WkT : WvT;
    const float*  bias = (z == 0) ? bq  : (z == 1) ? bk  : bv;
    const float   bscale = (z == 0) ? QSCL : 1.0f;
    const int t = threadIdx.x, w = t >> 6, lane = t & 63, q = lane >> 4, ln = lane & 15;
    const int m0 = blockIdx.x * 128;
    const int n0 = blockIdx.y * 128;
    const int wm = (w & 1) * 64, wn = (w >> 1) * 64;

    auto stage = [&](int buf, int kb) {
        #pragma unroll
        for (int j = 0; j < 4; ++j) {
            int row = w * 32 + j * 8 + (lane >> 3);
            int u = (lane & 7) ^ (row & 7);
            dma16(A + (size_t)(m0 + row) * 128 + kb * 64 + u * 8,
                  &a_s[buf][(w * 32 + j * 8) * 64]);
            dma16(BT + (size_t)(n0 + row) * 128 + kb * 64 + u * 8,
                  &b_s[buf][(w * 32 + j * 8) * 64]);
        }
    };

    f32x4 acc[4][4] = {};
    stage(0, 0);
    __syncthreads();
    stage(1, 1);
    #pragma unroll
    for (int kb = 0; kb < 2; ++kb) {
        if (kb == 1) __syncthreads();
        const bf16_t* as = a_s[kb];
        const bf16_t* bs = b_s[kb];
        #pragma unroll
        for (int kc = 0; kc < 2; ++kc) {
            bf16x8 af[4], bfr[4];
            #pragma unroll
            for (int mi = 0; mi < 4; ++mi)
                af[mi] = *(const bf16x8*)&as[(wm + mi * 16 + ln) * 64 + (((kc * 4 + q) ^ (ln & 7)) * 8)];
            #pragma unroll
            for (int ni = 0; ni < 4; ++ni)
                bfr[ni] = *(const bf16x8*)&bs[(wn + ni * 16 + ln) * 64 + (((kc * 4 + q) ^ (ln & 7)) * 8)];
            #pragma unroll
            for (int mi = 0; mi < 4; ++mi)
                #pragma unroll
                for (int ni = 0; ni < 4; ++ni)
                    acc[mi][ni] = MFMA_BF16(bfr[ni], af[mi], acc[mi][ni], 0, 0, 0);
        }
    }
    // C^T layout: acc[mi][ni] rows = d-local (q*4+r), cols = s-local (ln)
    if (z != 2) {
        bf16_t* out = (z == 0) ? Qh : Kh;
        const int b = m0 >> 11;
        #pragma unroll
        for (int ni = 0; ni < 4; ++ni) {
            int coln = n0 + wn + ni * 16 + q * 4;    // d base (mult of 4)
            int h = coln >> 7, d0 = coln & 127;
            f32x4 bv4 = *(const f32x4*)&bias[coln];
            #pragma unroll
            for (int mi = 0; mi < 4; ++mi) {
                int s = (m0 & 2047) + wm + mi * 16 + ln;
                bf16x4 pk;
                #pragma unroll
                for (int r = 0; r < 4; ++r)
                    pk[r] = (bf16_t)(acc[mi][ni][r] + bv4[r] * bscale);
                *(bf16x4*)&out[((size_t)(b * HH + h) * SS + s) * 128 + d0] = pk;
            }
        }
    } else {
        #pragma unroll
        for (int ni = 0; ni < 4; ++ni) {
            #pragma unroll
            for (int r = 0; r < 4; ++r) {
                int col = n0 + wn + ni * 16 + q * 4 + r;   // dout index
                int h = col >> 7, d = col & 127;
                float bvv = bias[col];
                #pragma unroll
                for (int mi = 0; mi < 4; ++mi) {
                    int mg = m0 + wm + mi * 16 + ln;        // s index
                    int b = mg >> 11, s = mg & 2047;
                    VhT[((size_t)(b * HH + h) * 128 + d) * SS + s] =
                        (bf16_t)(acc[mi][ni][r] + bvv);
                }
            }
        }
    }
}

// ---------------------------------------------------------------------------
// Attention (R4 golden): block = (bh, 128 q-rows), 4 waves x 32 rows, KV
// tiles of 64. DMA double-buffered swizzled K/V, 1 barrier/iter. Scores in
// log2 domain -> raw v_exp_f32. l via ones-MFMA. LDS 80 KB = 2 blocks/CU.
// ---------------------------------------------------------------------------
__global__ __launch_bounds__(256, 2)
void attn_kernel(const bf16_t* __restrict__ Qh, const bf16_t* __restrict__ Kh,
                 const bf16_t* __restrict__ VhT, bf16_t* __restrict__ Aout)
{
    __shared__ __align__(16) bf16_t k_s[2][64 * 128];
    __shared__ __align__(16) bf16_t v_s[2][128 * 64];
    __shared__ __align__(16) bf16_t p_s[4 * 32 * 64];
    const int t = threadIdx.x;
    const int w = t >> 6, lane = t & 63, q = lane >> 4, ln = lane & 15;
    const int bh = blockIdx.y;
    const int q0 = blockIdx.x * 128;
    const size_t hb = (size_t)bh * SS * 128;

    bf16x8 qf[2][4];
    #pragma unroll
    for (int rg = 0; rg < 2; ++rg) {
        const bf16_t* qrow = Qh + hb + (size_t)(q0 + w * 32 + rg * 16 + ln) * 128;
        #pragma unroll
        for (int kc = 0; kc < 4; ++kc)
            qf[rg][kc] = *(const bf16x8*)(qrow + kc * 32 + q * 8);
    }
    const bf16_t one = (bf16_t)1.0f;
    bf16x8 ones = { one, one, one, one, one, one, one, one };
    f32x4 o[2][8] = {};
    f32x4 ol[2] = {};
    bf16_t* pw = &p_s[w * 32 * 64];

    auto stage = [&](int buf, int kv0) {
        #pragma unroll
        for (int j = 0; j < 4; ++j) {           // K: 4 rows per inst
            int row = w * 16 + j * 4 + (lane >> 4);
            int blk = (lane & 15) ^ (row & 7);
            dma16(Kh + hb + (size_t)(kv0 + row) * 128 + blk * 8,
                  &k_s[buf][(w * 16 + j * 4) * 128]);
        }
        #pragma unroll
        for (int j = 0; j < 4; ++j) {           // V^T: 8 rows per inst
            int row = w * 32 + j * 8 + (lane >> 3);
            int blk = (lane & 7) ^ (row & 7);
            dma16(VhT + hb + (size_t)row * SS + kv0 + blk * 8,
                  &v_s[buf][(w * 32 + j * 8) * 64]);
        }
    };

    stage(0, 0);
    for (int it = 0; it < SS / 64; ++it) {
        int cur = it & 1;
        __syncthreads();                        // publish tile `it` (drains DMA)
        if (it + 1 < SS / 64) stage(cur ^ 1, (it + 1) * 64);
        const bf16_t* ks = &k_s[cur][0];
        const bf16_t* vs = &v_s[cur][0];
        // S^T = K * Q^T : C[key][qrow]  (log2-domain scores)
        f32x4 sc[2][4] = {};
        #pragma unroll
        for (int kc = 0; kc < 4; ++kc) {
            #pragma unroll
            for (int nt = 0; nt < 4; ++nt) {
                int row = nt * 16 + ln;
                bf16x8 kf = *(const bf16x8*)&ks[row * 128 + (((kc * 4 + q) ^ (ln & 7)) * 8)];
                sc[0][nt] = MFMA_BF16(kf, qf[0][kc], sc[0][nt], 0, 0, 0);
                sc[1][nt] = MFMA_BF16(kf, qf[1][kc], sc[1][nt], 0, 0, 0);
            }
        }
        // exp2 + swizzled P write (b64)
        #pragma unroll
        for (int rg = 0; rg < 2; ++rg) {
            #pragma unroll
            for (int nt = 0; nt < 4; ++nt) {
                bf16x4 pk;
                #pragma unroll
                for (int r = 0; r < 4; ++r)
                    pk[r] = (bf16_t)exp2_fast(sc[rg][nt][r]);
                int row = rg * 16 + ln;
                int blk = (2 * nt + (q >> 1)) ^ (row & 7);
                *(bf16x4*)&pw[row * 64 + blk * 8 + (q & 1) * 4] = pk;
            }
        }
        // PV + rowsum(l) via ones-MFMA; p wave-private: no barrier
        #pragma unroll
        for (int c2 = 0; c2 < 2; ++c2) {
            int pblk = (c2 * 4 + q) ^ (ln & 7);
            bf16x8 pf0 = *(const bf16x8*)&pw[ln * 64 + pblk * 8];
            bf16x8 pf1 = *(const bf16x8*)&pw[(16 + ln) * 64 + pblk * 8];
            ol[0] = MFMA_BF16(pf0, ones, ol[0], 0, 0, 0);
            ol[1] = MFMA_BF16(pf1, ones, ol[1], 0, 0, 0);
            #pragma unroll
            for (int dt = 0; dt < 8; ++dt) {
                int vrow = dt * 16 + ln;
                bf16x8 vf = *(const bf16x8*)&vs[vrow * 64 + (((c2 * 4 + q) ^ (vrow & 7)) * 8)];
                o[0][dt] = MFMA_BF16(pf0, vf, o[0][dt], 0, 0, 0);
                o[1][dt] = MFMA_BF16(pf1, vf, o[1][dt], 0, 0, 0);
            }
        }
    }
    const int b = bh >> 3, h = bh & 7;
    #pragma unroll
    for (int rg = 0; rg < 2; ++rg) {
        #pragma unroll
        for (int r = 0; r < 4; ++r) {
            float inv = 1.0f / ol[rg][r];
            int s = q0 + w * 32 + rg * 16 + q * 4 + r;
            bf16_t* dst = Aout + ((size_t)(b * SS + s)) * 1024 + h * 128;
            #pragma unroll
            for (int dt = 0; dt < 8; ++dt)
                dst[dt * 16 + ln] = (bf16_t)(o[rg][dt][r] * inv);
        }
    }
}

// ---------------------------------------------------------------------------
// Output projection: [8192][1024] @ WoT^T + bo -> fp32 d_out. Full K=1024,
// 16 DMA double-buffered steps. Tile 16m x 128n, 512 blocks, 4 blk/CU.
// ---------------------------------------------------------------------------
__global__ __launch_bounds__(256, 4)
void out_gemm(const bf16_t* __restrict__ A, const bf16_t* __restrict__ BT,
              const float* __restrict__ bias, float* __restrict__ out)
{
    __shared__ __align__(16) bf16_t a_s[2][16 * 64];
    __shared__ __align__(16) bf16_t b_s[2][128 * 64];
    const int t = threadIdx.x, w = t >> 6, lane = t & 63, q = lane >> 4, ln = lane & 15;
    const int m0 = blockIdx.x * 16;
    const int nh = w * 32;
    f32x4 acc[2] = {};

    auto stage = [&](int buf, int kk) {
        if (w == 0) {
            #pragma unroll
            for (int j = 0; j < 2; ++j) {
                int row = j * 8 + (lane >> 3);
                int u = (lane & 7) ^ (row & 7);
                dma16(A + (size_t)(m0 + row) * 1024 + kk + u * 8, &a_s[buf][(j * 8) * 64]);
            }
        }
        #pragma unroll
        for (int j = 0; j < 4; ++j) {
            int row = w * 32 + j * 8 + (lane >> 3);
            int u = (lane & 7) ^ (row & 7);
            dma16(BT + (size_t)row * 1024 + kk + u * 8, &b_s[buf][(w * 32 + j * 8) * 64]);
        }
    };

    stage(0, 0);
    for (int kb = 0; kb < 16; ++kb) {
        __syncthreads();
        if (kb < 15) stage((kb + 1) & 1, (kb + 1) * 64);
        const bf16_t* as = a_s[kb & 1];
        const bf16_t* bs = b_s[kb & 1];
        #pragma unroll
        for (int kc = 0; kc < 2; ++kc) {
            bf16x8 af = *(const bf16x8*)&as[ln * 64 + (((kc * 4 + q) ^ (ln & 7)) * 8)];
            #pragma unroll
            for (int ni = 0; ni < 2; ++ni) {
                int brow = nh + ni * 16 + ln;
                bf16x8 bfr = *(const bf16x8*)&bs[brow * 64 + (((kc * 4 + q) ^ (ln & 7)) * 8)];
                acc[ni] = MFMA_BF16(af, bfr, acc[ni], 0, 0, 0);
            }
        }
    }
    #pragma unroll
    for (int ni = 0; ni < 2; ++ni) {
        int col = nh + ni * 16 + ln;
        float bv = bias[col];
        #pragma unroll
        for (int r = 0; r < 4; ++r)
            out[(size_t)(m0 + q * 4 + r) * 128 + col] = acc[ni][r] + bv;
    }
}

// ---------------------------------------------------------------------------
extern "C" void kernel_launch(void* const* d_in, const int* in_sizes, int n_in,
                              void* d_out, int out_size, void* d_ws, size_t ws_size,
                              hipStream_t stream)
{
    const float* q  = (const float*)d_in[0];
    const float* k  = (const float*)d_in[1];
    const float* v  = (const float*)d_in[2];
    const float* Wq = (const float*)d_in[3];
    const float* bq = (const float*)d_in[4];
    const float* Wk = (const float*)d_in[5];
    const float* bk = (const float*)d_in[6];
    const float* Wv = (const float*)d_in[7];
    const float* bv = (const float*)d_in[8];
    const float* Wo = (const float*)d_in[9];
    const float* bo = (const float*)d_in[10];
    float* out = (float*)d_out;

    char* ws = (char*)d_ws;
    bf16_t* WqT  = (bf16_t*)(ws + 0 * (1 << 18));
    bf16_t* WkT  = (bf16_t*)(ws + 1 * (1 << 18));
    bf16_t* WvT  = (bf16_t*)(ws + 2 * (1 << 18));
    bf16_t* WoT  = (bf16_t*)(ws + 3 * (1 << 18));
    bf16_t* Abf  = (bf16_t*)(ws + (1 << 20));                   // [3][8192][128]
    bf16_t* Qh   = (bf16_t*)(ws + (1 << 23));                   // [B][H][S][128]
    bf16_t* Kh   = (bf16_t*)(ws + (1 << 23) + 1 * (1 << 24));   // [B][H][S][128]
    bf16_t* VhT  = (bf16_t*)(ws + (1 << 23) + 2 * (1 << 24));   // [B][H][128][S]
    bf16_t* Aout = (bf16_t*)(ws + (1 << 23) + 3 * (1 << 24));   // [B*S][1024]

    prep_kernel<<<896, 256, 0, stream>>>(q, k, v, Wq, Wk, Wv, Wo,
                                         WqT, WkT, WvT, WoT, Abf);
    proj_kernel<<<dim3(64, 8, 3), 256, 0, stream>>>(Abf, WqT, WkT, WvT,
                                                    bq, bk, bv, Qh, Kh, VhT);
    attn_kernel<<<dim3(SS / 128, BB * HH), 256, 0, stream>>>(Qh, Kh, VhT, Aout);
    out_gemm<<<512, 256, 0, stream>>>(Aout, WoT, bo, out);
}